// Round 11
// baseline (2881.544 us; speedup 1.0000x reference)
//
#include <hip/hip_runtime.h>

// Steerable pyramid, depthwise convs, NHWC fp32, C=16 (= 4 x float4).
// r11: LDS row staging. The binding resource (r2-r9 evidence) is the
// vector-load (TA/L1) port: sliding-window re-reads issued as global
// dwordx4 occupy it ~16cyc each. Fix: per block (one output row), stage
// each input row ONCE into LDS (double-buffered, T14 issue-early/
// write-late) and read taps via ds_read_b128 (separate LDS port).
// Global loads/block drop ~10x; kernels become VALU-bound.
// XCD-aware: n = blockIdx & 7. nt stores to d_out, cached to ws.

static __device__ __forceinline__ float4 f4z() { return make_float4(0.f, 0.f, 0.f, 0.f); }

static __device__ __forceinline__ float4 fmaf4(float f, float4 v, float4 a) {
    a.x = fmaf(f, v.x, a.x);
    a.y = fmaf(f, v.y, a.y);
    a.z = fmaf(f, v.z, a.z);
    a.w = fmaf(f, v.w, a.w);
    return a;
}

typedef __attribute__((ext_vector_type(4))) float f32x4;

static __device__ __forceinline__ void nt_store(float4* p, float4 v) {
    __builtin_nontemporal_store(*(const f32x4*)&v, (f32x4*)p);
}

// ---------------------------------------------------------------- pad helpers

__global__ __launch_bounds__(256) void pad_copy_img(
    const float4* __restrict__ src, float4* __restrict__ dst)
{
    const int W = 256, P = 4, Wp = 264;
    int n = blockIdx.x & 7;
    int q = blockIdx.x >> 3;                 // 1089 per n
    int e = q * 256 + threadIdx.x;
    int c4 = e & 3;
    int pix = e >> 2;
    int yp = pix / Wp;
    int xp = pix - yp * Wp;
    int y = yp - P, x = xp - P;
    bool ok = ((unsigned)y < (unsigned)W) && ((unsigned)x < (unsigned)W);
    int yc = min(max(y, 0), W - 1), xc = min(max(x, 0), W - 1);
    float4 v = src[(((n * W + yc) * W + xc) << 2) + c4];
    if (!ok) v = f4z();
    dst[((size_t)n * Wp * Wp + pix) * 4 + c4] = v;
}

__global__ __launch_bounds__(256) void zero_pads_all(
    float4* __restrict__ L0, float4* __restrict__ L1,
    float4* __restrict__ L2, float4* __restrict__ L3)
{
    int b = blockIdx.x;
    float4* buf; int W;
    if (b < 1056)      { buf = L0; W = 256; }
    else if (b < 1600) { buf = L1; W = 128; b -= 1056; }
    else if (b < 1888) { buf = L2; W = 64;  b -= 1600; }
    else               { buf = L3; W = 32;  b -= 1888; }
    int Wp = W + 16;
    int perN = 16 * Wp + 16 * W;
    int tid = b * 256 + threadIdx.x;
    int c4 = tid & 3;
    int p  = tid >> 2;
    int n  = p / perN;
    int r  = p - n * perN;
    int y, x;
    if (r < 16 * Wp) {
        int row = r / Wp;
        x = r - row * Wp;
        y = (row < 8) ? row : (W + row);
    } else {
        int q = r - 16 * Wp;
        y = 8 + (q >> 4);
        int xi = q & 15;
        x = (xi < 8) ? xi : (Wp - 16 + xi);
    }
    buf[((size_t)(n * Wp + y) * Wp + x) * 4 + c4] = f4z();
}

// ---------------------------------------------------------------- LDS convs

// hi0 + lo0 from padded image (pad 4, Wp=264). One output row per block.
// 256 thr = 4 c4 x 64 xg, 4 px/thread. grid 8*256.
__global__ __launch_bounds__(256, 3) void dual_lds(
    const float4* __restrict__ in,   // 264 wide, pad 4
    float4* __restrict__ hi0,        // flat 256 (d_out, nt)
    float4* __restrict__ lo0,        // 272 wide, pad 8 (ws, cached)
    const float* __restrict__ fh, const float* __restrict__ fl)
{
    const int Wp = 264, ROWE = Wp * 4, BLOCK = 256, NE = 5;
    __shared__ float4 lds[2][ROWE];
    int n = blockIdx.x & 7;
    int y = blockIdx.x >> 3;
    int t = threadIdx.x;
    int c4 = t & 3;
    int x0 = (t >> 2) * 4;

    const float4* rb = in + ((size_t)(n * Wp + y) * Wp) * 4;  // padded row y+dy

    // prologue: stage row 0
    for (int e = t; e < ROWE; e += BLOCK) lds[0][e] = rb[e];

    float4 acc[4][2];
    #pragma unroll
    for (int p = 0; p < 4; ++p) { acc[p][0] = f4z(); acc[p][1] = f4z(); }

    #pragma unroll
    for (int dy = 0; dy < 9; ++dy) {
        __syncthreads();
        float4 st[NE];
        if (dy < 8) {
            const float4* g = rb + (size_t)(dy + 1) * ROWE;
            #pragma unroll
            for (int i = 0; i < NE; ++i) {
                int e = t + i * BLOCK;
                st[i] = g[e < ROWE ? e : ROWE - 1];
            }
        }
        const float4* L = lds[dy & 1];
        float4 v[12];
        #pragma unroll
        for (int j = 0; j < 12; ++j) v[j] = L[(x0 + j) * 4 + c4];
        const float* wh = fh + dy * 9;
        const float* wl = fl + dy * 9;
        #pragma unroll
        for (int dx = 0; dx < 9; ++dx) {
            float h = wh[dx], l = wl[dx];
            #pragma unroll
            for (int p = 0; p < 4; ++p) {
                acc[p][0] = fmaf4(h, v[p + dx], acc[p][0]);
                acc[p][1] = fmaf4(l, v[p + dx], acc[p][1]);
            }
        }
        if (dy < 8) {
            float4* D = lds[(dy + 1) & 1];
            #pragma unroll
            for (int i = 0; i < NE; ++i) {
                int e = t + i * BLOCK;
                if (e < ROWE) D[e] = st[i];
            }
        }
    }

    size_t hidx = ((size_t)(n * 256 + y) * 256 + x0) * 4 + c4;
    size_t lidx = ((size_t)(n * 272 + y + 8) * 272 + x0 + 8) * 4 + c4;
    #pragma unroll
    for (int p = 0; p < 4; ++p) {
        nt_store(&hi0[hidx + p * 4], acc[p][0]);
        lo0[lidx + p * 4] = acc[p][1];
    }
}

// 4 band convs from padded (pad 8) lo. One output row per block.
// BLOCK = W threads (4 c4 x W/4 xg), 4 px/thread. grid 8*W.
template <int LOGW, int BLOCK>
__global__ __launch_bounds__(BLOCK, 3) void bands_lds(
    const float4* __restrict__ in,
    float4* __restrict__ b0, float4* __restrict__ b1,
    float4* __restrict__ b2, float4* __restrict__ b3,
    const float* __restrict__ bf)    // 4*81 contiguous
{
    const int W = 1 << LOGW, Wp = W + 16, ROWE = Wp * 4;
    const int NE = (ROWE + BLOCK - 1) / BLOCK;
    __shared__ float4 lds[2][ROWE];
    int n = blockIdx.x & 7;
    int y = blockIdx.x >> 3;
    int t = threadIdx.x;
    int c4 = t & 3;
    int x0 = (t >> 2) * 4;

    const float4* rb = in + ((size_t)(n * Wp + y + 4) * Wp) * 4; // padded row y+4+dy

    for (int e = t; e < ROWE; e += BLOCK) lds[0][e] = rb[e];

    float4 acc[4][4];                // [px][filter]
    #pragma unroll
    for (int p = 0; p < 4; ++p)
        #pragma unroll
        for (int f = 0; f < 4; ++f) acc[p][f] = f4z();

    #pragma unroll
    for (int dy = 0; dy < 9; ++dy) {
        __syncthreads();
        float4 st[NE];
        if (dy < 8) {
            const float4* g = rb + (size_t)(dy + 1) * ROWE;
            #pragma unroll
            for (int i = 0; i < NE; ++i) {
                int e = t + i * BLOCK;
                st[i] = g[e < ROWE ? e : ROWE - 1];
            }
        }
        const float4* L = lds[dy & 1];
        float4 v[12];
        #pragma unroll
        for (int j = 0; j < 12; ++j) v[j] = L[(x0 + 4 + j) * 4 + c4];
        const float* wr = bf + dy * 9;
        #pragma unroll
        for (int dx = 0; dx < 9; ++dx) {
            float w0 = wr[dx], w1 = wr[81 + dx], w2 = wr[162 + dx], w3 = wr[243 + dx];
            #pragma unroll
            for (int p = 0; p < 4; ++p) {
                acc[p][0] = fmaf4(w0, v[p + dx], acc[p][0]);
                acc[p][1] = fmaf4(w1, v[p + dx], acc[p][1]);
                acc[p][2] = fmaf4(w2, v[p + dx], acc[p][2]);
                acc[p][3] = fmaf4(w3, v[p + dx], acc[p][3]);
            }
        }
        if (dy < 8) {
            float4* D = lds[(dy + 1) & 1];
            #pragma unroll
            for (int i = 0; i < NE; ++i) {
                int e = t + i * BLOCK;
                if (e < ROWE) D[e] = st[i];
            }
        }
    }

    size_t idx = ((size_t)(n * W + y) * W + x0) * 4 + c4;
    #pragma unroll
    for (int p = 0; p < 4; ++p) {
        nt_store(&b0[idx + p * 4], acc[p][0]);
        nt_store(&b1[idx + p * 4], acc[p][1]);
        nt_store(&b2[idx + p * 4], acc[p][2]);
        nt_store(&b3[idx + p * 4], acc[p][3]);
    }
}

// 17x17 stride-2 downsample from padded (pad 8) lo. One output row per block.
// BLOCK = 2*Wo threads (4 c4 x Wo/2 xg), 2 px/thread. grid 8*Wo.
template <int LOGW, int BLOCK>
__global__ __launch_bounds__(BLOCK, 4) void down_lds(
    const float4* __restrict__ in, float4* __restrict__ lo_out,
    const float* __restrict__ lf)
{
    const int W = 1 << LOGW, Wo = W >> 1, Wp = W + 16, ROWE = Wp * 4;
    const int NE = (ROWE + BLOCK - 1) / BLOCK;
    __shared__ float4 lds[2][ROWE];
    int n = blockIdx.x & 7;
    int yo = blockIdx.x >> 3;
    int t = threadIdx.x;
    int c4 = t & 3;
    int xo0 = (t >> 2) * 2;

    const float4* rb = in + ((size_t)(n * Wp + 2 * yo) * Wp) * 4; // padded row 2yo+dy

    for (int e = t; e < ROWE; e += BLOCK) lds[0][e] = rb[e];

    float4 ac0 = f4z(), ac1 = f4z();

    #pragma unroll 1
    for (int dy = 0; dy < 17; ++dy) {
        __syncthreads();
        float4 st[NE];
        if (dy < 16) {
            const float4* g = rb + (size_t)(dy + 1) * ROWE;
            #pragma unroll
            for (int i = 0; i < NE; ++i) {
                int e = t + i * BLOCK;
                st[i] = g[e < ROWE ? e : ROWE - 1];
            }
        }
        const float4* L = lds[dy & 1];
        float4 v[19];
        #pragma unroll
        for (int j = 0; j < 19; ++j) v[j] = L[(2 * xo0 + j) * 4 + c4];
        const float* wp = lf + dy * 17;
        #pragma unroll
        for (int dx = 0; dx < 17; ++dx) {
            float w = wp[dx];
            ac0 = fmaf4(w, v[dx], ac0);
            ac1 = fmaf4(w, v[dx + 2], ac1);
        }
        if (dy < 16) {
            float4* D = lds[(dy + 1) & 1];
            #pragma unroll
            for (int i = 0; i < NE; ++i) {
                int e = t + i * BLOCK;
                if (e < ROWE) D[e] = st[i];
            }
        }
    }

    const int W1 = Wo + 16;
    size_t oidx = ((size_t)(n * W1 + yo + 8) * W1 + xo0 + 8) * 4 + c4;
    lo_out[oidx] = ac0;
    lo_out[oidx + 4] = ac1;
}

// ------------------------------------- scales 2..3 fused (round-9 structure)

template <int LOGW>
__global__ __launch_bounds__(256, 4) void scale_fused2(
    const float4* __restrict__ in,
    float4* __restrict__ b0, float4* __restrict__ b1,
    float4* __restrict__ b2, float4* __restrict__ b3,
    float4* __restrict__ lo_out,
    const float* __restrict__ bf, const float* __restrict__ lf,
    int outPad)
{
    const int W = 1 << LOGW, Wp = W + 16;
    const int bandsPerN = (W * W) >> 7;
    int n = blockIdx.x & 7;
    int q = blockIdx.x >> 3;
    int t = threadIdx.x;
    int c4 = t & 3;

    if (q < bandsPerN) {
        int xg2 = (t >> 2) & (W / 2 - 1);
        int ry = t >> (LOGW + 1);
        int y = q * (1 << (7 - LOGW)) + ry;
        int x0 = xg2 * 2;
        const float4* rp = in + ((size_t)(n * Wp + y + 4) * Wp + (x0 + 4)) * 4 + c4;
        const size_t rstep = (size_t)Wp * 4;

        float4 a00 = f4z(), a01 = f4z(), a02 = f4z(), a03 = f4z();
        float4 a10 = f4z(), a11 = f4z(), a12 = f4z(), a13 = f4z();
        #pragma unroll 1
        for (int dy = 0; dy < 9; ++dy) {
            float4 v[10];
            #pragma unroll
            for (int j = 0; j < 10; ++j) v[j] = rp[j * 4];
            rp += rstep;
            const float* wr = bf + dy * 9;
            #pragma unroll
            for (int dx = 0; dx < 9; ++dx) {
                float w0 = wr[dx], w1 = wr[81 + dx], w2 = wr[162 + dx], w3 = wr[243 + dx];
                a00 = fmaf4(w0, v[dx], a00);
                a01 = fmaf4(w1, v[dx], a01);
                a02 = fmaf4(w2, v[dx], a02);
                a03 = fmaf4(w3, v[dx], a03);
                a10 = fmaf4(w0, v[dx + 1], a10);
                a11 = fmaf4(w1, v[dx + 1], a11);
                a12 = fmaf4(w2, v[dx + 1], a12);
                a13 = fmaf4(w3, v[dx + 1], a13);
            }
        }
        size_t idx = ((size_t)(n * W + y) * W + x0) * 4 + c4;
        nt_store(&b0[idx], a00); nt_store(&b0[idx + 4], a10);
        nt_store(&b1[idx], a01); nt_store(&b1[idx + 4], a11);
        nt_store(&b2[idx], a02); nt_store(&b2[idx + 4], a12);
        nt_store(&b3[idx], a03); nt_store(&b3[idx + 4], a13);
    } else {
        const int Wo = W >> 1;
        int q2 = q - bandsPerN;
        int xg2 = (t >> 2) & (Wo / 2 - 1);
        int ry = t >> LOGW;
        int yo = q2 * (1 << (8 - LOGW)) + ry;
        int xo0 = xg2 * 2;
        const float4* rp = in + ((size_t)(n * Wp + 2 * yo) * Wp + 2 * xo0) * 4 + c4;
        const size_t rstep = (size_t)Wp * 4;

        float4 ac0 = f4z(), ac1 = f4z();
        #pragma unroll 1
        for (int dy = 0; dy < 17; ++dy) {
            float4 v[19];
            #pragma unroll
            for (int j = 0; j < 19; ++j) v[j] = rp[j * 4];
            rp += rstep;
            const float* wp = lf + dy * 17;
            #pragma unroll
            for (int dx = 0; dx < 17; ++dx) {
                float w = wp[dx];
                ac0 = fmaf4(w, v[dx], ac0);
                ac1 = fmaf4(w, v[dx + 2], ac1);
            }
        }
        int W1 = Wo + 2 * outPad;
        size_t oidx = ((size_t)(n * W1 + yo + outPad) * W1 + xo0 + outPad) * 4 + c4;
        if (outPad == 0) {
            nt_store(&lo_out[oidx], ac0);
            nt_store(&lo_out[oidx + 4], ac1);
        } else {
            lo_out[oidx] = ac0;
            lo_out[oidx + 4] = ac1;
        }
    }
}

// ---------------------------------------------------------------- launch

extern "C" void kernel_launch(void* const* d_in, const int* in_sizes, int n_in,
                              void* d_out, int out_size, void* d_ws, size_t ws_size,
                              hipStream_t stream) {
    const float* image   = (const float*)d_in[0];
    const float* lo0filt = (const float*)d_in[1];
    const float* hi0filt = (const float*)d_in[2];
    const float* lofilt  = (const float*)d_in[3];
    const float* bfilts  = (const float*)d_in[4];
    float* out = (float*)d_out;
    float* ws  = (float*)d_ws;

    const int N = 8, C = 16;
    size_t sz[5];
    const int Ws[5] = {256, 128, 64, 32, 16};
    for (int s = 0; s < 5; ++s) sz[s] = (size_t)N * Ws[s] * Ws[s] * C;

    // Workspace: P0 = image pad4 (264^2); L0..L3 = lo0..lo3 pad8.
    float* P0 = ws;
    float* L0 = P0 + (size_t)N * 264 * 264 * C;
    float* L1 = L0 + (size_t)N * 272 * 272 * C;
    float* L2 = L1 + (size_t)N * 144 * 144 * C;
    float* L3 = L2 + (size_t)N * 80 * 80 * C;

    // Output layout (reversed pyramid, flat):
    // [ lo_final | s=3 b=3..0 | s=2 b=3..0 | s=1 b=3..0 | s=0 b=3..0 | hi0 ]
    float* out_lofinal = out;
    size_t o = sz[4];
    float* band_ptr[4][4];
    for (int s = 3; s >= 0; --s)
        for (int b = 3; b >= 0; --b) { band_ptr[s][b] = out + o; o += sz[s]; }
    float* out_hi0 = out + o;

    // 1. zero pad borders of L0..L3
    zero_pads_all<<<2048, 256, 0, stream>>>(
        (float4*)L0, (float4*)L1, (float4*)L2, (float4*)L3);
    // 2. image -> P0 (pad 4)
    pad_copy_img<<<8 * 1089, 256, 0, stream>>>(
        (const float4*)image, (float4*)P0);
    // 3. hi0 (nt) + lo0 (cached), LDS-staged
    dual_lds<<<8 * 256, 256, 0, stream>>>(
        (const float4*)P0, (float4*)out_hi0, (float4*)L0, hi0filt, lo0filt);
    // 4. lo1 = down(lo0), LDS-staged
    down_lds<8, 256><<<8 * 128, 256, 0, stream>>>(
        (const float4*)L0, (float4*)L1, lofilt);
    // 5. bands s=0, LDS-staged
    bands_lds<8, 256><<<8 * 256, 256, 0, stream>>>(
        (const float4*)L0, (float4*)band_ptr[0][0], (float4*)band_ptr[0][1],
        (float4*)band_ptr[0][2], (float4*)band_ptr[0][3], bfilts);
    // 6. lo2 = down(lo1)
    down_lds<7, 128><<<8 * 64, 128, 0, stream>>>(
        (const float4*)L1, (float4*)L2, lofilt);
    // 7. bands s=1
    bands_lds<7, 128><<<8 * 128, 128, 0, stream>>>(
        (const float4*)L1, (float4*)band_ptr[1][0], (float4*)band_ptr[1][1],
        (float4*)band_ptr[1][2], (float4*)band_ptr[1][3], bfilts);
    // 8..9. scales 2..3 fused (bands + down)
    scale_fused2<6><<<8 * (32 + 8), 256, 0, stream>>>(
        (const float4*)L2, (float4*)band_ptr[2][0], (float4*)band_ptr[2][1],
        (float4*)band_ptr[2][2], (float4*)band_ptr[2][3], (float4*)L3,
        bfilts, lofilt, 8);
    scale_fused2<5><<<8 * (8 + 2), 256, 0, stream>>>(
        (const float4*)L3, (float4*)band_ptr[3][0], (float4*)band_ptr[3][1],
        (float4*)band_ptr[3][2], (float4*)band_ptr[3][3], (float4*)out_lofinal,
        bfilts, lofilt, 0);
}

// Round 12
// 476.039 us; speedup vs baseline: 6.0532x; 6.0532x over previous
//
#include <hip/hip_runtime.h>

// Steerable pyramid via MFMA (bf16 matrix cores), fp32 I/O.
// Depthwise conv as banded-matrix MFMA: D[px][ch] = sum_dy A_dy * B_dy,
// A_dy[m][k] = filt[dy][k-m-shift] (built in regs once per wave),
// B_dy[k][c] = input row (y+dy) in channel-major bf16 layout [n][y][c][x].
// mfma_f32_16x16x32_bf16: A lane: m=l&15, k=(l>>4)*8+i; B lane: c=l&15,
// k=(l>>4)*8+i; D lane: c=l&15, m=(l>>4)*4+reg  [m89-verified C/D].
// Threshold is 2% of per-output absmax; bf16 error ~0.5-1% -> passes.

typedef __attribute__((ext_vector_type(8))) short short8v;
typedef __attribute__((ext_vector_type(4))) float f32x4;

static __device__ __forceinline__ unsigned short f2bf(float f) {
    union { float f; unsigned u; } v; v.f = f;
    unsigned u = v.u;
    u += 0x7fffu + ((u >> 16) & 1u);
    return (unsigned short)(u >> 16);
}

static __device__ __forceinline__ unsigned pack2(float a, float b) {
    return (unsigned)f2bf(a) | ((unsigned)f2bf(b) << 16);
}

static __device__ __forceinline__ void nt_storef(float* p, float v) {
    __builtin_nontemporal_store(v, p);
}

// ---------------------------------------------------------------- staging

// fp32 NHWC image -> bf16 CX buffer [n][yp 264][c 16][x 264], pad 4, zeros.
__global__ __launch_bounds__(256) void img_to_cx(
    const float* __restrict__ src, unsigned short* __restrict__ dst)
{
    const int Wp = 264;
    __shared__ unsigned short lds[16][264];
    int n = blockIdx.x & 7;
    int yp = blockIdx.x >> 3;
    int t = threadIdx.x;
    int y = yp - 4;
    bool rowOK = (unsigned)y < 256u;
    if (rowOK) {
        for (int x = t; x < Wp; x += 256) {
            int xs = x - 4;
            bool ok = (unsigned)xs < 256u;
            const float* p = src + (((size_t)(n * 256 + y) * 256 + (ok ? xs : 0)) << 4);
            #pragma unroll
            for (int c = 0; c < 16; ++c) {
                float v = ok ? p[c] : 0.f;
                lds[c][x] = f2bf(v);
            }
        }
        __syncthreads();
        for (int task = t; task < 16 * 33; task += 256) {
            int c = task / 33, ch = task % 33;
            short8v v = *(const short8v*)&lds[c][ch * 8];
            *(short8v*)(dst + ((size_t)(n * 264 + yp) * 16 + c) * 264 + ch * 8) = v;
        }
    } else {
        short8v z = {0, 0, 0, 0, 0, 0, 0, 0};
        for (int task = t; task < 16 * 33; task += 256) {
            int c = task / 33, ch = task % 33;
            *(short8v*)(dst + ((size_t)(n * 264 + yp) * 16 + c) * 264 + ch * 8) = z;
        }
    }
}

// Zero pad borders (8 wide) of the 4 CX lo buffers + 64B slack after IMG.
static __device__ __forceinline__ void zero_cx(unsigned short* buf, int W, int tid) {
    int Wp = W + 16;
    int perN = 16 * 16 * Wp + W * 16 * 16;
    int n = tid / perN;
    int r = tid % perN;
    int y, c, x;
    if (r < 16 * 16 * Wp) {
        int ry = r / (16 * Wp);
        int rem = r % (16 * Wp);
        c = rem / Wp;
        x = rem % Wp;
        y = (ry < 8) ? ry : ry + W;          // rows 0..7 and W+8..W+15
    } else {
        int r2 = r - 16 * 16 * Wp;
        y = 8 + (r2 >> 8);
        c = (r2 >> 4) & 15;
        int xi = r2 & 15;
        x = (xi < 8) ? xi : xi + W;          // cols 0..7 and W+8..W+15
    }
    buf[((size_t)(n * Wp + y) * 16 + c) * Wp + x] = 0;
}

__global__ __launch_bounds__(256) void zero_pads_cx(
    unsigned short* __restrict__ L0, unsigned short* __restrict__ L1,
    unsigned short* __restrict__ L2, unsigned short* __restrict__ L3,
    unsigned short* __restrict__ imgSlack)
{
    int b = blockIdx.x, t = threadIdx.x;
    if (b < 4224)      zero_cx(L0, 256, b * 256 + t);
    else if (b < 6400) zero_cx(L1, 128, (b - 4224) * 256 + t);
    else if (b < 7552) zero_cx(L2, 64,  (b - 6400) * 256 + t);
    else if (b < 8192) zero_cx(L3, 32,  (b - 7552) * 256 + t);
    else if (t < 32)   imgSlack[t] = 0;
}

// ---------------------------------------------------------------- MFMA convs

#define MFMA_BF16 __builtin_amdgcn_mfma_f32_16x16x32_bf16

// hi0 + lo0 from IMG CX (pad 4). 512 blocks: n=b&7, q=b>>3: xseg=q&15, yq=q>>4.
// Each wave: 16 consecutive y tiles at x0 = xseg*16.
__global__ __launch_bounds__(256, 2) void dual_mfma(
    const unsigned short* __restrict__ img,
    float* __restrict__ hi0, unsigned short* __restrict__ lo0,
    const float* __restrict__ fh, const float* __restrict__ fl)
{
    const int RS = 16 * 264;
    int n = blockIdx.x & 7;
    int q = blockIdx.x >> 3;
    int xseg = q & 15, yq = q >> 4;
    int t = threadIdx.x, wv = t >> 6, l = t & 63;
    int m = l & 15, g = l >> 4, kb = g * 8;
    int x0 = xseg * 16;
    int ybase = (yq * 4 + wv) * 16;

    short8v Ah[9], Al[9];
    #pragma unroll
    for (int dy = 0; dy < 9; ++dy) {
        const float* fhr = fh + dy * 9;
        const float* flr = fl + dy * 9;
        short8v ah, al;
        #pragma unroll
        for (int i = 0; i < 8; ++i) {
            int d = kb + i - m;                      // col = x0 + k = x + dx
            bool ok = (d >= 0) && (d < 9);
            ah[i] = (short)(ok ? f2bf(fhr[d]) : 0);
            al[i] = (short)(ok ? f2bf(flr[d]) : 0);
        }
        Ah[dy] = ah; Al[dy] = al;
    }

    #pragma unroll 1
    for (int ty = 0; ty < 16; ++ty) {
        int y = ybase + ty;
        const unsigned short* base =
            img + ((size_t)(n * 264 + y) * 16 + m) * 264 + x0 + kb;
        f32x4 ach = {0, 0, 0, 0}, acl = {0, 0, 0, 0};
        #pragma unroll
        for (int dy = 0; dy < 9; ++dy) {
            short8v B = *(const short8v*)(base + (size_t)dy * RS);
            ach = MFMA_BF16(Ah[dy], B, ach, 0, 0, 0);
            acl = MFMA_BF16(Al[dy], B, acl, 0, 0, 0);
        }
        size_t ob = ((size_t)(n * 256 + y) * 256 + x0 + g * 4) * 16 + m;
        #pragma unroll
        for (int r = 0; r < 4; ++r) nt_storef(hi0 + ob + (size_t)r * 16, ach[r]);
        size_t lb = ((size_t)(n * 272 + y + 8) * 16 + m) * 272 + (x0 + 8 + g * 4);
        *(unsigned*)(lo0 + lb)     = pack2(acl[0], acl[1]);
        *(unsigned*)(lo0 + lb + 2) = pack2(acl[2], acl[3]);
    }
}

// 4 band convs from CX lo (pad 8). A shift: col = x0 + k, k = m + dx + 4.
template <int LOGW, int YPW>
__global__ __launch_bounds__(256, 2) void bands_mfma(
    const unsigned short* __restrict__ in,
    float* __restrict__ b0, float* __restrict__ b1,
    float* __restrict__ b2, float* __restrict__ b3,
    const float* __restrict__ bf)
{
    const int W = 1 << LOGW, Wp = W + 16, XS = W / 16, RS = 16 * Wp;
    int n = blockIdx.x & 7;
    int q = blockIdx.x >> 3;
    int xseg = q & (XS - 1), yq = q >> (LOGW - 4);
    int t = threadIdx.x, wv = t >> 6, l = t & 63;
    int m = l & 15, g = l >> 4, kb = g * 8;
    int x0 = xseg * 16;
    int ybase = (yq * 4 + wv) * YPW;

    short8v A[9][4];
    #pragma unroll
    for (int dy = 0; dy < 9; ++dy)
        #pragma unroll
        for (int f = 0; f < 4; ++f) {
            const float* fr = bf + f * 81 + dy * 9;
            short8v a;
            #pragma unroll
            for (int i = 0; i < 8; ++i) {
                int d = kb + i - m - 4;
                a[i] = (short)((d >= 0 && d < 9) ? f2bf(fr[d]) : 0);
            }
            A[dy][f] = a;
        }

    #pragma unroll 1
    for (int ty = 0; ty < YPW; ++ty) {
        int y = ybase + ty;
        const unsigned short* base =
            in + ((size_t)(n * Wp + y + 4) * 16 + m) * Wp + x0 + kb;
        f32x4 a0 = {0,0,0,0}, a1 = {0,0,0,0}, a2 = {0,0,0,0}, a3 = {0,0,0,0};
        #pragma unroll
        for (int dy = 0; dy < 9; ++dy) {
            short8v B = *(const short8v*)(base + (size_t)dy * RS);
            a0 = MFMA_BF16(A[dy][0], B, a0, 0, 0, 0);
            a1 = MFMA_BF16(A[dy][1], B, a1, 0, 0, 0);
            a2 = MFMA_BF16(A[dy][2], B, a2, 0, 0, 0);
            a3 = MFMA_BF16(A[dy][3], B, a3, 0, 0, 0);
        }
        size_t ob = ((size_t)(n * W + y) * W + x0 + g * 4) * 16 + m;
        #pragma unroll
        for (int r = 0; r < 4; ++r) {
            nt_storef(b0 + ob + (size_t)r * 16, a0[r]);
            nt_storef(b1 + ob + (size_t)r * 16, a1[r]);
            nt_storef(b2 + ob + (size_t)r * 16, a2[r]);
            nt_storef(b3 + ob + (size_t)r * 16, a3[r]);
        }
    }
}

// 17x17 stride-2 downsample from CX lo (pad 8). col = 2*x0 + k, k = 2m + dx.
// Two MFMAs per dy (k-split 0..31 / 32..47); lanes g>=2 have A2==0 so their
// B2 address is clamped to B1 (in-bounds, value irrelevant).
template <int LOGW, int YPW, bool OUTF32>
__global__ __launch_bounds__(256, 2) void down_mfma(
    const unsigned short* __restrict__ in, void* __restrict__ outp,
    const float* __restrict__ lf)
{
    const int W = 1 << LOGW, Wpi = W + 16, Wo = W >> 1, Wpo = Wo + 16;
    const int XS = Wo / 16, RS = 16 * Wpi;
    int n = blockIdx.x & 7;
    int q = blockIdx.x >> 3;
    int xseg = q & (XS - 1), yq = q >> (LOGW - 5);
    int t = threadIdx.x, wv = t >> 6, l = t & 63;
    int m = l & 15, g = l >> 4, kb = g * 8;
    int x0 = xseg * 16;
    int ybase = (yq * 4 + wv) * YPW;
    int off2 = (g < 2) ? 32 : 0;

    short8v A1[17], A2[17];
    #pragma unroll
    for (int dy = 0; dy < 17; ++dy) {
        const float* fr = lf + dy * 17;
        short8v a1, a2;
        #pragma unroll
        for (int i = 0; i < 8; ++i) {
            int d1 = kb + i - 2 * m;
            int d2 = 32 + kb + i - 2 * m;
            a1[i] = (short)((d1 >= 0 && d1 < 17) ? f2bf(fr[d1]) : 0);
            a2[i] = (short)((d2 >= 0 && d2 < 17) ? f2bf(fr[d2]) : 0);
        }
        A1[dy] = a1; A2[dy] = a2;
    }

    #pragma unroll 1
    for (int ty = 0; ty < YPW; ++ty) {
        int yo = ybase + ty;
        const unsigned short* base =
            in + ((size_t)(n * Wpi + 2 * yo) * 16 + m) * Wpi + 2 * x0 + kb;
        f32x4 aA = {0, 0, 0, 0}, aB = {0, 0, 0, 0};
        #pragma unroll
        for (int dy = 0; dy < 17; ++dy) {
            short8v B1 = *(const short8v*)(base + (size_t)dy * RS);
            short8v B2 = *(const short8v*)(base + (size_t)dy * RS + off2);
            aA = MFMA_BF16(A1[dy], B1, aA, 0, 0, 0);
            aB = MFMA_BF16(A2[dy], B2, aB, 0, 0, 0);
        }
        f32x4 acc = aA + aB;
        if (OUTF32) {
            float* o = (float*)outp;
            size_t ob = ((size_t)(n * Wo + yo) * Wo + x0 + g * 4) * 16 + m;
            #pragma unroll
            for (int r = 0; r < 4; ++r) nt_storef(o + ob + (size_t)r * 16, acc[r]);
        } else {
            unsigned short* o = (unsigned short*)outp;
            size_t lb = ((size_t)(n * Wpo + yo + 8) * 16 + m) * Wpo + (x0 + 8 + g * 4);
            *(unsigned*)(o + lb)     = pack2(acc[0], acc[1]);
            *(unsigned*)(o + lb + 2) = pack2(acc[2], acc[3]);
        }
    }
}

// ---------------------------------------------------------------- launch

extern "C" void kernel_launch(void* const* d_in, const int* in_sizes, int n_in,
                              void* d_out, int out_size, void* d_ws, size_t ws_size,
                              hipStream_t stream) {
    const float* image   = (const float*)d_in[0];
    const float* lo0filt = (const float*)d_in[1];
    const float* hi0filt = (const float*)d_in[2];
    const float* lofilt  = (const float*)d_in[3];
    const float* bfilts  = (const float*)d_in[4];
    float* out = (float*)d_out;

    const int N = 8, C = 16;
    size_t sz[5];
    const int Ws[5] = {256, 128, 64, 32, 16};
    for (int s = 0; s < 5; ++s) sz[s] = (size_t)N * Ws[s] * Ws[s] * C;

    // Workspace (ushort units): IMG CX (264^2 pad4) + slack, L0..L3 CX pad8.
    unsigned short* wsu = (unsigned short*)d_ws;
    unsigned short* IMG = wsu;
    size_t imgE = (size_t)N * 264 * 16 * 264;
    unsigned short* IMGSLACK = IMG + imgE;
    unsigned short* L0 = IMGSLACK + 32;
    unsigned short* L1 = L0 + (size_t)N * 272 * 16 * 272;
    unsigned short* L2 = L1 + (size_t)N * 144 * 16 * 144;
    unsigned short* L3 = L2 + (size_t)N * 80 * 16 * 80;

    // Output layout (reversed pyramid, flat):
    // [ lo_final | s=3 b=3..0 | s=2 b=3..0 | s=1 b=3..0 | s=0 b=3..0 | hi0 ]
    float* out_lofinal = out;
    size_t o = sz[4];
    float* band_ptr[4][4];
    for (int s = 3; s >= 0; --s)
        for (int b = 3; b >= 0; --b) { band_ptr[s][b] = out + o; o += sz[s]; }
    float* out_hi0 = out + o;

    zero_pads_cx<<<8193, 256, 0, stream>>>(L0, L1, L2, L3, IMGSLACK);
    img_to_cx<<<2112, 256, 0, stream>>>(image, IMG);
    dual_mfma<<<512, 256, 0, stream>>>(IMG, out_hi0, L0, hi0filt, lo0filt);
    down_mfma<8, 16, false><<<128, 256, 0, stream>>>(L0, L1, lofilt);
    bands_mfma<8, 16><<<512, 256, 0, stream>>>(
        L0, band_ptr[0][0], band_ptr[0][1], band_ptr[0][2], band_ptr[0][3], bfilts);
    down_mfma<7, 16, false><<<32, 256, 0, stream>>>(L1, L2, lofilt);
    bands_mfma<7, 16><<<128, 256, 0, stream>>>(
        L1, band_ptr[1][0], band_ptr[1][1], band_ptr[1][2], band_ptr[1][3], bfilts);
    down_mfma<6, 8, false><<<16, 256, 0, stream>>>(L2, L3, lofilt);
    bands_mfma<6, 16><<<32, 256, 0, stream>>>(
        L2, band_ptr[2][0], band_ptr[2][1], band_ptr[2][2], band_ptr[2][3], bfilts);
    down_mfma<5, 4, true><<<8, 256, 0, stream>>>(L3, out_lofinal, lofilt);
    bands_mfma<5, 8><<<16, 256, 0, stream>>>(
        L3, band_ptr[3][0], band_ptr[3][1], band_ptr[3][2], band_ptr[3][3], bfilts);
}